// Round 1
// 205.519 us; speedup vs baseline: 1.0729x; 1.0729x over previous
//
#include <hip/hip_runtime.h>
#include <math.h>

// Problem constants (fixed by setup_inputs)
constexpr int Bb = 128;   // batch
constexpr int Nn = 2048;  // input capsules
constexpr int Dd = 8;     // input capsule dim
constexpr int Jj = 32;    // output capsules
constexpr int Pp = 16;    // output capsule dim

// Tiling: R4/R7-proven config. 512-thread blocks, 8 waves, BT=2 batches/wave.
// GRID=512 -> 2 blocks/CU, 16 waves/CU.
constexpr int BT = 2;
constexpr int WV = 8;
constexpr int BB = BT * WV;      // 16 batches per block
constexpr int BN = 32;           // n per block
constexpr int NBC = Bb / BB;     // 8
constexpr int NNC = Nn / BN;     // 64
constexpr int GRID = NBC * NNC;  // 512
constexpr int SZ = Bb * Jj * Pp; // 65536 floats

typedef _Float16 half2v __attribute__((ext_vector_type(2)));
typedef _Float16 half8  __attribute__((ext_vector_type(8)));
typedef float    floatx4 __attribute__((ext_vector_type(4)));

#if __has_builtin(__builtin_amdgcn_fdot2)
__device__ inline float fdot2(half2v a, half2v b, float c) {
    return __builtin_amdgcn_fdot2(a, b, c, false);
}
#else
__device__ inline float fdot2(half2v a, half2v b, float c) {
    return (float)a.x * (float)b.x + (float)a.y * (float)b.y + c;
}
#endif

__device__ inline half2v bch2(unsigned u) { return __builtin_bit_cast(half2v, u); }
__device__ inline half8  bch8(uint4 u)    { return __builtin_bit_cast(half8, u); }
__device__ inline unsigned pkh2(float lo, float hi) {
    half2v h; h.x = (_Float16)lo; h.y = (_Float16)hi;   // v_cvt_f16_f32 (RTN)
    return __builtin_bit_cast(unsigned, h);
}

// ============================================================================
// Pass 0 as a pure MFMA GEMM (NEW this round).
// With uniform c (softmax of zero logits), s0[b,jp] = (1/J) sum_{n,i} x*W:
// a single GEMM, M=jp=512, N=b=128, K=(n,i)=16384. No routing structure.
// Decomposition mirrors route_k: 64 n-chunks (K-slices of 256) x 8 b-groups,
// same XCD swizzle, writes the same 64 partial slices Sp[nc][b][jp] so
// reduce_squash_k is reused verbatim.
// Per block (256 thr, 4 waves): jp=512 x b=16, K=256 in 8 steps of 32 (4 n).
// W staged per K-step as fp16 [ns(4)][jp(512)][i(8)] (32 KB, double-buffered),
// x staged once as fp16 [n(32)][b(16)][i(8)] (8 KB). LDS total 72 KB ->
// 2 blocks/CU. MFMA v_mfma_f32_16x16x32_f16: A-frag = W' row (lane&15 within
// jp-tile), k-group = lane>>4 (one 8-i n-group = one uint4); B-frag = x row.
// C layout (verified, guide §3): col=lane&15=b, row=(lane>>4)*4+reg=jp.
// ============================================================================
__global__ __launch_bounds__(256, 2)
void gemm0_k(const float* __restrict__ x, const float* __restrict__ W,
             float* __restrict__ S)
{
    __shared__ uint4 wl[2][4 * 512];   // 2 x 32 KB fp16 W slice [ns][jp]
    __shared__ uint4 xl[32 * 16];      // 8 KB fp16 x tile [n][b]

    const int tid  = threadIdx.x;
    const int wave = tid >> 6;
    const int lane = tid & 63;

    const int id  = blockIdx.x;
    const int xcd = id & 7;
    const int bc  = (id >> 3) & 7;     // b-group: 8 sharers of W slice, same XCD
    const int nch = id >> 6;
    const int nc  = xcd + 8 * nch;     // 0..63 n-chunk
    const int b0  = bc * 16;
    const int n0  = nc * 32;

    // ---- stage x tile once: idx -> (n = idx&31, b = idx>>5); coalesced 32B ----
    #pragma unroll
    for (int r = 0; r < 2; ++r) {
        int idx = r * 256 + tid;
        int n = idx & 31, b = idx >> 5;
        const float4* src = reinterpret_cast<const float4*>(
            x + ((size_t)(b0 + b) * Nn + n0 + n) * Dd);
        float4 a = src[0], c4 = src[1];
        uint4 o;
        o.x = pkh2(a.x, a.y);   o.y = pkh2(a.z, a.w);
        o.z = pkh2(c4.x, c4.y); o.w = pkh2(c4.z, c4.w);
        xl[n * 16 + b] = o;
    }

    // ---- W staging: per K-step, 8 chunks/thread: cc = r*256+tid = ns*512+jp ----
    const float4* Wg = reinterpret_cast<const float4*>(W);
    float4 wa[8], wb[8];
    auto wload = [&](int ks) {
        #pragma unroll
        for (int r = 0; r < 8; ++r) {
            int cc = r * 256 + tid;
            int jp = cc & 511, ns = cc >> 9;
            int j = jp >> 4, p = jp & 15;
            size_t base = ((size_t)j * Nn + (n0 + ks * 4 + ns)) * 32 + p * 2;
            wa[r] = Wg[base];
            wb[r] = Wg[base + 1];
        }
    };
    auto wstore = [&](int buf) {
        #pragma unroll
        for (int r = 0; r < 8; ++r) {
            int cc = r * 256 + tid;
            uint4 o;
            o.x = pkh2(wa[r].x, wa[r].y); o.y = pkh2(wa[r].z, wa[r].w);
            o.z = pkh2(wb[r].x, wb[r].y); o.w = pkh2(wb[r].z, wb[r].w);
            wl[buf][cc] = o;
        }
    };

    floatx4 acc[8];
    #pragma unroll
    for (int f = 0; f < 8; ++f)
        #pragma unroll
        for (int q = 0; q < 4; ++q) acc[f][q] = 0.f;

    wload(0);
    wstore(0);
    __syncthreads();

    const int arow = lane & 15;   // row within 16-tile (jp for A, b for B)
    const int kg   = lane >> 4;   // k-group 0..3 -> ns

    for (int ks = 0; ks < 8; ++ks) {
        if (ks + 1 < 8) wload(ks + 1);          // prefetch next slice to regs
        const int buf = ks & 1;

        half8 bfrag = bch8(xl[(ks * 4 + kg) * 16 + arow]);
        #pragma unroll
        for (int f = 0; f < 8; ++f) {
            half8 afrag = bch8(wl[buf][kg * 512 + wave * 128 + f * 16 + arow]);
            acc[f] = __builtin_amdgcn_mfma_f32_16x16x32_f16(afrag, bfrag, acc[f], 0, 0, 0);
        }

        if (ks + 1 < 8) {
            __syncthreads();                    // all frag reads of other buf done
            wstore((ks + 1) & 1);
            __syncthreads();
        }
    }

    // ---- write partial slice Sp[nc][b][jp]; 4 regs = 4 consecutive jp ----
    float* out = S + (size_t)nc * SZ;
    const int bcol = b0 + arow;
    #pragma unroll
    for (int f = 0; f < 8; ++f) {
        size_t off = (size_t)bcol * 512 + wave * 128 + f * 16 + kg * 4;
        *reinterpret_cast<float4*>(out + off) =
            make_float4(acc[f][0], acc[f][1], acc[f][2], acc[f][3]);
    }
}

// Routing pass. R7-VERBATIM (proven: 56 us/pass, 52 VGPR, 0 bank conflicts,
// clean partial stores). W staged per-n in LDS as fp16 (8 KB/slice, double-
// buffered), x tile fp16, u_hat via v_dot2_f32_f16 (fp32 accumulate).
// Swizzled W layout: chunk (l = j*2+hp, pp) at slot pp*64 + ((l+pp)&63).
// XCD swizzle (verified R4: FETCH 139->26 MB): 8 bc-sharers share blockIdx&7.
// Lessons: R5/R6 = no hoisted index arrays / no unroll pragmas / BT=2 only;
// R8 = cooperative launch unsupported by harness.
template<int LOGITS, int ATOMIC>
__global__ __launch_bounds__(512, 4)
void route_k(const float* __restrict__ x, const float* __restrict__ W,
             const float* __restrict__ OS, float* __restrict__ S)
{
    __shared__ uint4 wbuf[2][512];   // 2 x 8 KB fp16 W double buffer
    __shared__ uint4 xs[BB * BN];    // 8 KB fp16 x tile: [b][n] -> 8 halves

    const int tid  = threadIdx.x;
    const int wave = tid >> 6;
    const int lane = tid & 63;

    const int id  = blockIdx.x;
    const int xcd = id & 7;
    const int bc  = (id >> 3) & 7;
    const int nch = id >> 6;               // 0..7
    const int nc  = xcd + 8 * nch;         // 0..63
    const int b0  = bc * BB;
    const int n0  = nc * BN;
    const int j   = lane >> 1;
    const int hp  = lane & 1;              // p-half

    // ---- stage x tile as fp16: thread t -> (b = t>>5, n = t&31) ----
    {
        const int b = tid >> 5, n = tid & 31;
        const float4* src = reinterpret_cast<const float4*>(
            x + ((size_t)(b0 + b) * Nn + n0 + n) * Dd);
        float4 a = src[0], c4 = src[1];
        uint4 o;
        o.x = pkh2(a.x, a.y);  o.y = pkh2(a.z, a.w);
        o.z = pkh2(c4.x, c4.y); o.w = pkh2(c4.z, c4.w);
        xs[b * BN + n] = o;
    }

    // ---- W staging: thread t -> (j = t>>4, p = t&15); 2 float4 -> 1 uint4 ----
    const float4* Wg = reinterpret_cast<const float4*>(W);
    const int sj = tid >> 4;          // j
    const int sp = tid & 15;          // p
    const int sl = sj * 2 + (sp >> 3);          // l for this chunk
    const int spp = sp & 7;                     // pp
    const int wslot = spp * 64 + ((sl + spp) & 63);

    float4 sta, stb;
    auto load_slice = [&](int n) {
        const size_t base = (size_t)n * 32 + sp * 2 + (size_t)sj * ((size_t)Nn * 32);
        sta = Wg[base];
        stb = Wg[base + 1];
    };
    auto store_slice = [&](int buf) {
        uint4 o;
        o.x = pkh2(sta.x, sta.y);  o.y = pkh2(sta.z, sta.w);
        o.z = pkh2(stb.x, stb.y);  o.w = pkh2(stb.z, stb.w);
        wbuf[buf][wslot] = o;
    };

    // Output-sum fragment for logits
    float osum[BT][8];
    if (LOGITS) {
        #pragma unroll
        for (int bb = 0; bb < BT; ++bb) {
            const float4* op = reinterpret_cast<const float4*>(
                OS + ((size_t)(b0 + wave * BT + bb) * Jj + j) * Pp + hp * 8);
            float4 a = op[0], b4 = op[1];
            osum[bb][0] = a.x;  osum[bb][1] = a.y;  osum[bb][2] = a.z;  osum[bb][3] = a.w;
            osum[bb][4] = b4.x; osum[bb][5] = b4.y; osum[bb][6] = b4.z; osum[bb][7] = b4.w;
        }
    }

    float Sa[BT][8];
    #pragma unroll
    for (int bb = 0; bb < BT; ++bb)
        #pragma unroll
        for (int pp = 0; pp < 8; ++pp) Sa[bb][pp] = 0.f;

    load_slice(n0);
    store_slice(0);
    __syncthreads();

    const uint4* xw = xs + (size_t)(wave * BT) * BN;   // this wave's x rows

    for (int nn = 0; nn < BN; ++nn) {
        if (nn + 1 < BN) load_slice(n0 + nn + 1);  // prefetch next slice to regs
        const int buf = nn & 1;

        // x rows (LDS broadcast, one b128 per batch): 8 halves = 4 half2
        half2v x01[BT], x23[BT], x45[BT], x67[BT];
        #pragma unroll
        for (int bb = 0; bb < BT; ++bb) {
            uint4 xr = xw[(size_t)bb * BN + nn];
            x01[bb] = bch2(xr.x); x23[bb] = bch2(xr.y);
            x45[bb] = bch2(xr.z); x67[bb] = bch2(xr.w);
        }

        // u_hat via fdot2 (f16 inputs, fp32 accumulate); no hadds needed
        float uh[BT][8];
        #pragma unroll
        for (int pp = 0; pp < 8; ++pp) {
            uint4 wv = wbuf[buf][pp * 64 + ((lane + pp) & 63)];
            half2v w01 = bch2(wv.x), w23 = bch2(wv.y);
            half2v w45 = bch2(wv.z), w67 = bch2(wv.w);
            #pragma unroll
            for (int bb = 0; bb < BT; ++bb) {
                float acc = fdot2(w01, x01[bb], 0.f);
                acc = fdot2(w23, x23[bb], acc);
                acc = fdot2(w45, x45[bb], acc);
                acc = fdot2(w67, x67[bb], acc);
                uh[bb][pp] = acc;
            }
        }

        if (!LOGITS) {
            #pragma unroll
            for (int bb = 0; bb < BT; ++bb)
                #pragma unroll
                for (int pp = 0; pp < 8; ++pp) Sa[bb][pp] += uh[bb][pp];
        } else {
            #pragma unroll
            for (int bb = 0; bb < BT; ++bb) {
                float lg = 0.f;
                #pragma unroll
                for (int pp = 0; pp < 8; ++pp)
                    lg = fmaf(osum[bb][pp], uh[bb][pp], lg);
                lg += __shfl_xor(lg, 1, 64);   // merge p-halves: full 16-p dot
                // softmax over j (no max-subtract; |lg| small): butterfly
                float e = __expf(lg);
                float se = e;
                #pragma unroll
                for (int mk = 2; mk <= 32; mk <<= 1)
                    se += __shfl_xor(se, mk, 64);
                float c = e * __builtin_amdgcn_rcpf(se);
                #pragma unroll
                for (int pp = 0; pp < 8; ++pp)
                    Sa[bb][pp] = fmaf(c, uh[bb][pp], Sa[bb][pp]);
            }
        }

        if (nn + 1 < BN) {
            store_slice((nn + 1) & 1);
            __syncthreads();
        }
    }

    // ---- flush block-partial S ----
    #pragma unroll
    for (int bb = 0; bb < BT; ++bb) {
        const size_t off = ((size_t)(b0 + wave * BT + bb) * Jj + j) * Pp + hp * 8;
        if (ATOMIC) {
            float* spd = S + off;
            #pragma unroll
            for (int pp = 0; pp < 8; ++pp) atomicAdd(spd + pp, Sa[bb][pp]);
        } else {
            float4* dst = reinterpret_cast<float4*>(S + (size_t)nc * SZ + off);
            dst[0] = make_float4(Sa[bb][0], Sa[bb][1], Sa[bb][2], Sa[bb][3]);
            dst[1] = make_float4(Sa[bb][4], Sa[bb][5], Sa[bb][6], Sa[bb][7]);
        }
    }
}

// Reduce nparts partial S slices, then squash.
// mode 0: OS = v; 1: OS += v; 2: out = v.
// R9: re-gridded 256 blocks x 64 threads (one float4/thread) so the 16.8 MB
// partial read spreads over all 256 CUs instead of 64 (was ~10 us, now ~3).
__global__ void reduce_squash_k(const float* __restrict__ Sp, int nparts,
                                float scale, float* __restrict__ OS,
                                float* __restrict__ out, int mode)
{
    const int t = blockIdx.x * 64 + threadIdx.x;   // 0..16383
    const float4* sp = reinterpret_cast<const float4*>(Sp);
    float4 a = make_float4(0.f, 0.f, 0.f, 0.f);
    #pragma unroll 8
    for (int s = 0; s < nparts; ++s) {
        float4 v = sp[(size_t)s * (SZ / 4) + t];
        a.x += v.x; a.y += v.y; a.z += v.z; a.w += v.w;
    }
    a.x *= scale; a.y *= scale; a.z *= scale; a.w *= scale;
    float s2 = a.x * a.x + a.y * a.y + a.z * a.z + a.w * a.w;
    s2 += __shfl_xor(s2, 1, 64);   // 16 p = 4 consecutive threads
    s2 += __shfl_xor(s2, 2, 64);
    const float g = s2 / ((1.f + s2) * sqrtf(s2 + 1e-7f));
    float4 v = make_float4(g * a.x, g * a.y, g * a.z, g * a.w);
    if (mode == 0) {
        reinterpret_cast<float4*>(OS)[t] = v;
    } else if (mode == 1) {
        float4 o = reinterpret_cast<float4*>(OS)[t];
        o.x += v.x; o.y += v.y; o.z += v.z; o.w += v.w;
        reinterpret_cast<float4*>(OS)[t] = o;
    } else {
        reinterpret_cast<float4*>(out)[t] = v;
    }
}

extern "C" void kernel_launch(void* const* d_in, const int* in_sizes, int n_in,
                              void* d_out, int out_size, void* d_ws, size_t ws_size,
                              hipStream_t stream)
{
    const float* x = (const float*)d_in[0];   // [128, 2048, 8]
    const float* W = (const float*)d_in[1];   // [32, 2048, 16, 8]
    float* out = (float*)d_out;               // [128, 32, 16]

    const bool part = ws_size >= (size_t)(NNC + 1) * SZ * sizeof(float); // 16.9 MB
    dim3 rg(GRID), rb(512);
    dim3 sg(SZ / 4 / 64), sb(64);             // 256 blocks x 64 threads

    if (part) {
        float* Sp = (float*)d_ws;                 // [64][65536] partials
        float* OS = Sp + (size_t)NNC * SZ;        // running output sum

        gemm0_k<<<dim3(GRID), dim3(256), 0, stream>>>(x, W, Sp);
        reduce_squash_k<<<sg, sb, 0, stream>>>(Sp, NNC, 1.f / Jj, OS, out, 0);

        route_k<1, 0><<<rg, rb, 0, stream>>>(x, W, OS, Sp);
        reduce_squash_k<<<sg, sb, 0, stream>>>(Sp, NNC, 1.f, OS, out, 1);

        route_k<1, 0><<<rg, rb, 0, stream>>>(x, W, OS, Sp);
        reduce_squash_k<<<sg, sb, 0, stream>>>(Sp, NNC, 1.f, OS, out, 2);
    } else {
        float* S  = (float*)d_ws;
        float* OS = S + SZ;
        const size_t Sbytes = (size_t)SZ * sizeof(float);

        hipMemsetAsync(S, 0, Sbytes, stream);
        route_k<0, 1><<<rg, rb, 0, stream>>>(x, W, nullptr, S);
        reduce_squash_k<<<sg, sb, 0, stream>>>(S, 1, 1.f / Jj, OS, out, 0);

        hipMemsetAsync(S, 0, Sbytes, stream);
        route_k<1, 1><<<rg, rb, 0, stream>>>(x, W, OS, S);
        reduce_squash_k<<<sg, sb, 0, stream>>>(S, 1, 1.f, OS, out, 1);

        hipMemsetAsync(S, 0, Sbytes, stream);
        route_k<1, 1><<<rg, rb, 0, stream>>>(x, W, OS, S);
        reduce_squash_k<<<sg, sb, 0, stream>>>(S, 1, 1.f, OS, out, 2);
    }
}

// Round 2
// 204.289 us; speedup vs baseline: 1.0793x; 1.0060x over previous
//
#include <hip/hip_runtime.h>
#include <math.h>

// Problem constants (fixed by setup_inputs)
constexpr int Bb = 128;   // batch
constexpr int Nn = 2048;  // input capsules
constexpr int Dd = 8;     // input capsule dim
constexpr int Jj = 32;    // output capsules
constexpr int Pp = 16;    // output capsule dim

// Routing-pass tiling (R4/R7-proven): 512-thread blocks, 8 waves, BT=2.
constexpr int BT = 2;
constexpr int WV = 8;
constexpr int BB = BT * WV;      // 16 batches per block
constexpr int BN = 32;           // n per block
constexpr int NBC = Bb / BB;     // 8
constexpr int NNC = Nn / BN;     // 64
constexpr int GRID = NBC * NNC;  // 512
constexpr int SZ = Bb * Jj * Pp; // 65536 floats
constexpr size_t W16_ELEMS = (size_t)Jj * Nn * Pp * Dd;  // 8.39M halfs = 16.8 MB

typedef _Float16 half2v __attribute__((ext_vector_type(2)));
typedef _Float16 half8  __attribute__((ext_vector_type(8)));
typedef float    floatx4 __attribute__((ext_vector_type(4)));

#if __has_builtin(__builtin_amdgcn_fdot2)
__device__ inline float fdot2(half2v a, half2v b, float c) {
    return __builtin_amdgcn_fdot2(a, b, c, false);
}
#else
__device__ inline float fdot2(half2v a, half2v b, float c) {
    return (float)a.x * (float)b.x + (float)a.y * (float)b.y + c;
}
#endif

__device__ inline half2v bch2(unsigned u) { return __builtin_bit_cast(half2v, u); }
__device__ inline half8  bch8(uint4 u)    { return __builtin_bit_cast(half8, u); }
__device__ inline unsigned pkh2(float lo, float hi) {
    half2v h; h.x = (_Float16)lo; h.y = (_Float16)hi;   // v_cvt_f16_f32 (RTN)
    return __builtin_bit_cast(unsigned, h);
}

// ============================================================================
// Pass 0 GEMM, v2 (R2). v1 was ~41 us: 8 b-sharing blocks per W chunk put
// 4 MB of live fp32 W per XCD-L2 -> thrash -> ~256 MB of L3/HBM traffic.
// v2: each block covers ALL 128 b (8 waves x 16 b), so every W byte is read
// exactly once (33.5 MB total, streamed; no L2 reuse required).
// Grid 512 = jpc(8, 64-jp cols) x nc(64, 32-n K-slices); 2 blocks/CU.
// XCD swizzle: 8 jpc-sharers of one x-chunk share id&7.
// Write-through: converts W to fp16 (same RTN as pkh2 path) into ws for the
// routing passes -- each (jp,n) region written by exactly one block.
// Writes the same Sp[64][b][jp] partials (different jpc -> disjoint columns).
// ============================================================================
template<int WT>
__global__ __launch_bounds__(512, 2)
void gemm0_k2(const float* __restrict__ x, const float* __restrict__ W,
              ushort* __restrict__ W16, float* __restrict__ S)
{
    __shared__ uint4 wl[2][256];   // [ns(4)][jpr(64)] fp16 W slice, dbuf (8 KB)
    __shared__ uint4 xl[2][512];   // [ns(4)][b(128)]  fp16 x slice, dbuf (16 KB)

    const int tid  = threadIdx.x;
    const int wave = tid >> 6;
    const int lane = tid & 63;

    const int id  = blockIdx.x;
    const int xcd = id & 7;
    const int rem = id >> 3;
    const int jpc = rem & 7;           // 8 jp-chunks of 64
    const int nch = rem >> 3;          // 0..7
    const int nc  = xcd + 8 * nch;     // 0..63 n-chunk (K-slice)
    const int jp0 = jpc * 64;
    const int n0  = nc * 32;

    // W staging ids (threads < 256): chunk (ns = t>>6, jpr = t&63)
    const int wns = (tid >> 6) & 3;
    const int wjpr = tid & 63;
    const int wjp = jp0 + wjpr, wj = wjp >> 4, wp = wjp & 15;
    // x staging ids (all threads): (b = t>>2, q = t&3); q = n-sub
    const int xb = tid >> 2, xq = tid & 3;

    const float4* Wg = reinterpret_cast<const float4*>(W);
    const float4* Xg = reinterpret_cast<const float4*>(x);
    uint4* W16v = reinterpret_cast<uint4*>(W16);

    float4 wa, wb2, xa, xb2;
    auto load_t = [&](int ks) {
        const int n = n0 + ks * 4;
        if (tid < 256) {
            const size_t base = ((size_t)wj * 2048 + (n + wns)) * 32 + wp * 2;
            wa = Wg[base]; wb2 = Wg[base + 1];
        }
        const size_t xbase = ((size_t)xb * 2048 + n) * 2 + xq * 2;
        xa = Xg[xbase]; xb2 = Xg[xbase + 1];
    };
    auto store_t = [&](int buf, int ks) {
        if (tid < 256) {
            uint4 o;
            o.x = pkh2(wa.x, wa.y);   o.y = pkh2(wa.z, wa.w);
            o.z = pkh2(wb2.x, wb2.y); o.w = pkh2(wb2.z, wb2.w);
            wl[buf][tid] = o;
            if (WT)
                W16v[((size_t)wj * 2048 + (n0 + ks * 4 + wns)) * 16 + wp] = o;
        }
        uint4 o2;
        o2.x = pkh2(xa.x, xa.y);   o2.y = pkh2(xa.z, xa.w);
        o2.z = pkh2(xb2.x, xb2.y); o2.w = pkh2(xb2.z, xb2.w);
        xl[buf][xq * 128 + xb] = o2;
    };

    floatx4 acc[4];
    #pragma unroll
    for (int f = 0; f < 4; ++f)
        #pragma unroll
        for (int q = 0; q < 4; ++q) acc[f][q] = 0.f;

    load_t(0);
    store_t(0, 0);
    __syncthreads();

    const int kg = lane >> 4;     // k-group -> ns (n within slice)
    const int ar = lane & 15;     // row within 16-tile

    for (int ks = 0; ks < 8; ++ks) {
        if (ks < 7) load_t(ks + 1);          // prefetch next slice to regs
        const int buf = ks & 1;

        half8 bfrag = bch8(xl[buf][kg * 128 + wave * 16 + ar]);
        #pragma unroll
        for (int f = 0; f < 4; ++f) {
            half8 afrag = bch8(wl[buf][kg * 64 + f * 16 + ar]);
            acc[f] = __builtin_amdgcn_mfma_f32_16x16x32_f16(afrag, bfrag, acc[f], 0, 0, 0);
        }

        if (ks < 7) {                         // single barrier per K-step:
            store_t(buf ^ 1, ks + 1);         // store targets other buffer
            __syncthreads();
        }
    }

    // ---- write partial slice Sp[nc][b][jp]; C layout: col=b, row=jp-sub ----
    float* outp = S + (size_t)nc * SZ;
    const int bcol = wave * 16 + ar;
    #pragma unroll
    for (int f = 0; f < 4; ++f) {
        const size_t off = (size_t)bcol * 512 + jp0 + f * 16 + kg * 4;
        *reinterpret_cast<float4*>(outp + off) =
            make_float4(acc[f][0], acc[f][1], acc[f][2], acc[f][3]);
    }
}

// Routing pass (R7 math, verbatim). R2: template W16F stages W from the
// pre-converted fp16 W16 (1 uint4 load, no cvt; slot->(j,p) mapping is the
// inverse of the compute-side swizzle so reads are untouched).
// Swizzled W layout: chunk (l = j*2+hp, pp) at slot pp*64 + ((l+pp)&63).
// Lessons: R5/R6 = no hoisted index arrays / no unroll pragmas / BT=2 only;
// R8 = cooperative launch unsupported by harness.
template<int LOGITS, int ATOMIC, int W16F>
__global__ __launch_bounds__(512, 4)
void route_k(const float* __restrict__ x, const float* __restrict__ W,
             const ushort* __restrict__ W16,
             const float* __restrict__ OS, float* __restrict__ S)
{
    __shared__ uint4 wbuf[2][512];   // 2 x 8 KB fp16 W double buffer
    __shared__ uint4 xs[BB * BN];    // 8 KB fp16 x tile: [b][n] -> 8 halves

    const int tid  = threadIdx.x;
    const int wave = tid >> 6;
    const int lane = tid & 63;

    const int id  = blockIdx.x;
    const int xcd = id & 7;
    const int bc  = (id >> 3) & 7;
    const int nch = id >> 6;               // 0..7
    const int nc  = xcd + 8 * nch;         // 0..63
    const int b0  = bc * BB;
    const int n0  = nc * BN;
    const int j   = lane >> 1;
    const int hp  = lane & 1;              // p-half

    // ---- stage x tile as fp16: thread t -> (b = t>>5, n = t&31) ----
    {
        const int b = tid >> 5, n = tid & 31;
        const float4* src = reinterpret_cast<const float4*>(
            x + ((size_t)(b0 + b) * Nn + n0 + n) * Dd);
        float4 a = src[0], c4 = src[1];
        uint4 o;
        o.x = pkh2(a.x, a.y);  o.y = pkh2(a.z, a.w);
        o.z = pkh2(c4.x, c4.y); o.w = pkh2(c4.z, c4.w);
        xs[b * BN + n] = o;
    }

    // ---- W staging ----
    // fp32 path: thread t -> (j = t>>4, p = t&15), cvt, swizzled slot.
    const float4* Wg = reinterpret_cast<const float4*>(W);
    const int sj = tid >> 4;
    const int sp = tid & 15;
    const int sl = sj * 2 + (sp >> 3);
    const int spp = sp & 7;
    const int wslot = spp * 64 + ((sl + spp) & 63);
    // fp16 path: thread t stages slot t; invert slot->(j,p).
    const int ispp = tid >> 6;
    const int isl  = ((tid & 63) - ispp) & 63;
    const int isj  = isl >> 1;
    const int isp  = ((isl & 1) << 3) | ispp;
    const uint4* W16v = reinterpret_cast<const uint4*>(W16);
    const size_t wbase16 = (size_t)isj * 32768 + isp;   // uint4 units

    float4 sta, stb;
    uint4 st16;
    auto load_slice = [&](int n) {
        if (W16F) {
            st16 = W16v[wbase16 + (size_t)n * 16];
        } else {
            const size_t base = (size_t)n * 32 + sp * 2 + (size_t)sj * ((size_t)Nn * 32);
            sta = Wg[base];
            stb = Wg[base + 1];
        }
    };
    auto store_slice = [&](int buf) {
        if (W16F) {
            wbuf[buf][tid] = st16;
        } else {
            uint4 o;
            o.x = pkh2(sta.x, sta.y);  o.y = pkh2(sta.z, sta.w);
            o.z = pkh2(stb.x, stb.y);  o.w = pkh2(stb.z, stb.w);
            wbuf[buf][wslot] = o;
        }
    };

    // Output-sum fragment for logits
    float osum[BT][8];
    if (LOGITS) {
        #pragma unroll
        for (int bb = 0; bb < BT; ++bb) {
            const float4* op = reinterpret_cast<const float4*>(
                OS + ((size_t)(b0 + wave * BT + bb) * Jj + j) * Pp + hp * 8);
            float4 a = op[0], b4 = op[1];
            osum[bb][0] = a.x;  osum[bb][1] = a.y;  osum[bb][2] = a.z;  osum[bb][3] = a.w;
            osum[bb][4] = b4.x; osum[bb][5] = b4.y; osum[bb][6] = b4.z; osum[bb][7] = b4.w;
        }
    }

    float Sa[BT][8];
    #pragma unroll
    for (int bb = 0; bb < BT; ++bb)
        #pragma unroll
        for (int pp = 0; pp < 8; ++pp) Sa[bb][pp] = 0.f;

    load_slice(n0);
    store_slice(0);
    __syncthreads();

    const uint4* xw = xs + (size_t)(wave * BT) * BN;   // this wave's x rows

    for (int nn = 0; nn < BN; ++nn) {
        if (nn + 1 < BN) load_slice(n0 + nn + 1);  // prefetch next slice to regs
        const int buf = nn & 1;

        // x rows (LDS broadcast, one b128 per batch): 8 halves = 4 half2
        half2v x01[BT], x23[BT], x45[BT], x67[BT];
        #pragma unroll
        for (int bb = 0; bb < BT; ++bb) {
            uint4 xr = xw[(size_t)bb * BN + nn];
            x01[bb] = bch2(xr.x); x23[bb] = bch2(xr.y);
            x45[bb] = bch2(xr.z); x67[bb] = bch2(xr.w);
        }

        // u_hat via fdot2 (f16 inputs, fp32 accumulate)
        float uh[BT][8];
        #pragma unroll
        for (int pp = 0; pp < 8; ++pp) {
            uint4 wv = wbuf[buf][pp * 64 + ((lane + pp) & 63)];
            half2v w01 = bch2(wv.x), w23 = bch2(wv.y);
            half2v w45 = bch2(wv.z), w67 = bch2(wv.w);
            #pragma unroll
            for (int bb = 0; bb < BT; ++bb) {
                float acc = fdot2(w01, x01[bb], 0.f);
                acc = fdot2(w23, x23[bb], acc);
                acc = fdot2(w45, x45[bb], acc);
                acc = fdot2(w67, x67[bb], acc);
                uh[bb][pp] = acc;
            }
        }

        if (!LOGITS) {
            #pragma unroll
            for (int bb = 0; bb < BT; ++bb)
                #pragma unroll
                for (int pp = 0; pp < 8; ++pp) Sa[bb][pp] += uh[bb][pp];
        } else {
            #pragma unroll
            for (int bb = 0; bb < BT; ++bb) {
                float lg = 0.f;
                #pragma unroll
                for (int pp = 0; pp < 8; ++pp)
                    lg = fmaf(osum[bb][pp], uh[bb][pp], lg);
                lg += __shfl_xor(lg, 1, 64);   // merge p-halves: full 16-p dot
                // softmax over j (no max-subtract; |lg| small): butterfly
                float e = __expf(lg);
                float se = e;
                #pragma unroll
                for (int mk = 2; mk <= 32; mk <<= 1)
                    se += __shfl_xor(se, mk, 64);
                float c = e * __builtin_amdgcn_rcpf(se);
                #pragma unroll
                for (int pp = 0; pp < 8; ++pp)
                    Sa[bb][pp] = fmaf(c, uh[bb][pp], Sa[bb][pp]);
            }
        }

        if (nn + 1 < BN) {
            store_slice((nn + 1) & 1);
            __syncthreads();
        }
    }

    // ---- flush block-partial S ----
    #pragma unroll
    for (int bb = 0; bb < BT; ++bb) {
        const size_t off = ((size_t)(b0 + wave * BT + bb) * Jj + j) * Pp + hp * 8;
        if (ATOMIC) {
            float* spd = S + off;
            #pragma unroll
            for (int pp = 0; pp < 8; ++pp) atomicAdd(spd + pp, Sa[bb][pp]);
        } else {
            float4* dst = reinterpret_cast<float4*>(S + (size_t)nc * SZ + off);
            dst[0] = make_float4(Sa[bb][0], Sa[bb][1], Sa[bb][2], Sa[bb][3]);
            dst[1] = make_float4(Sa[bb][4], Sa[bb][5], Sa[bb][6], Sa[bb][7]);
        }
    }
}

// Reduce nparts partial S slices, then squash. mode 0: OS=v; 1: OS+=v; 2: out=v.
// R9: 256 blocks x 64 threads spreads the 16.8 MB read over all 256 CUs.
__global__ void reduce_squash_k(const float* __restrict__ Sp, int nparts,
                                float scale, float* __restrict__ OS,
                                float* __restrict__ out, int mode)
{
    const int t = blockIdx.x * 64 + threadIdx.x;   // 0..16383
    const float4* sp = reinterpret_cast<const float4*>(Sp);
    float4 a = make_float4(0.f, 0.f, 0.f, 0.f);
    #pragma unroll 8
    for (int s = 0; s < nparts; ++s) {
        float4 v = sp[(size_t)s * (SZ / 4) + t];
        a.x += v.x; a.y += v.y; a.z += v.z; a.w += v.w;
    }
    a.x *= scale; a.y *= scale; a.z *= scale; a.w *= scale;
    float s2 = a.x * a.x + a.y * a.y + a.z * a.z + a.w * a.w;
    s2 += __shfl_xor(s2, 1, 64);   // 16 p = 4 consecutive threads
    s2 += __shfl_xor(s2, 2, 64);
    const float g = s2 / ((1.f + s2) * sqrtf(s2 + 1e-7f));
    float4 v = make_float4(g * a.x, g * a.y, g * a.z, g * a.w);
    if (mode == 0) {
        reinterpret_cast<float4*>(OS)[t] = v;
    } else if (mode == 1) {
        float4 o = reinterpret_cast<float4*>(OS)[t];
        o.x += v.x; o.y += v.y; o.z += v.z; o.w += v.w;
        reinterpret_cast<float4*>(OS)[t] = o;
    } else {
        reinterpret_cast<float4*>(out)[t] = v;
    }
}

extern "C" void kernel_launch(void* const* d_in, const int* in_sizes, int n_in,
                              void* d_out, int out_size, void* d_ws, size_t ws_size,
                              hipStream_t stream)
{
    const float* x = (const float*)d_in[0];   // [128, 2048, 8]
    const float* W = (const float*)d_in[1];   // [32, 2048, 16, 8]
    float* out = (float*)d_out;               // [128, 32, 16]

    const size_t needSp = (size_t)(NNC + 1) * SZ * sizeof(float);   // 16.9 MB
    const bool part  = ws_size >= needSp;
    const bool w16ok = ws_size >= needSp + W16_ELEMS * sizeof(ushort); // +16.8 MB
    dim3 rg(GRID), rb(512);
    dim3 sg(SZ / 4 / 64), sb(64);             // 256 blocks x 64 threads

    if (part) {
        float* Sp = (float*)d_ws;                 // [64][65536] partials
        float* OS = Sp + (size_t)NNC * SZ;        // running output sum
        ushort* W16 = (ushort*)(OS + SZ);         // fp16 W (if w16ok)

        if (w16ok) {
            gemm0_k2<1><<<dim3(512), rb, 0, stream>>>(x, W, W16, Sp);
            reduce_squash_k<<<sg, sb, 0, stream>>>(Sp, NNC, 1.f / Jj, OS, out, 0);

            route_k<1, 0, 1><<<rg, rb, 0, stream>>>(x, W, W16, OS, Sp);
            reduce_squash_k<<<sg, sb, 0, stream>>>(Sp, NNC, 1.f, OS, out, 1);

            route_k<1, 0, 1><<<rg, rb, 0, stream>>>(x, W, W16, OS, Sp);
            reduce_squash_k<<<sg, sb, 0, stream>>>(Sp, NNC, 1.f, OS, out, 2);
        } else {
            gemm0_k2<0><<<dim3(512), rb, 0, stream>>>(x, W, nullptr, Sp);
            reduce_squash_k<<<sg, sb, 0, stream>>>(Sp, NNC, 1.f / Jj, OS, out, 0);

            route_k<1, 0, 0><<<rg, rb, 0, stream>>>(x, W, nullptr, OS, Sp);
            reduce_squash_k<<<sg, sb, 0, stream>>>(Sp, NNC, 1.f, OS, out, 1);

            route_k<1, 0, 0><<<rg, rb, 0, stream>>>(x, W, nullptr, OS, Sp);
            reduce_squash_k<<<sg, sb, 0, stream>>>(Sp, NNC, 1.f, OS, out, 2);
        }
    } else {
        float* S  = (float*)d_ws;
        float* OS = S + SZ;
        const size_t Sbytes = (size_t)SZ * sizeof(float);

        hipMemsetAsync(S, 0, Sbytes, stream);
        route_k<0, 1, 0><<<rg, rb, 0, stream>>>(x, W, nullptr, nullptr, S);
        reduce_squash_k<<<sg, sb, 0, stream>>>(S, 1, 1.f / Jj, OS, out, 0);

        hipMemsetAsync(S, 0, Sbytes, stream);
        route_k<1, 1, 0><<<rg, rb, 0, stream>>>(x, W, nullptr, OS, S);
        reduce_squash_k<<<sg, sb, 0, stream>>>(S, 1, 1.f, OS, out, 1);

        hipMemsetAsync(S, 0, Sbytes, stream);
        route_k<1, 1, 0><<<rg, rb, 0, stream>>>(x, W, nullptr, OS, S);
        reduce_squash_k<<<sg, sb, 0, stream>>>(S, 1, 1.f, OS, out, 2);
    }
}